// Round 1
// baseline (1230.305 us; speedup 1.0000x reference)
//
#include <hip/hip_runtime.h>
#include <hip/hip_bf16.h>
#include <math.h>

// ---------------------------------------------------------------------------
// GCN classifier pipeline, fp32.
//   L1: t = x @ Wg1            ; a = aggregate(t) ; stats(a)  (bias cancels in BN)
//   L2: t = bnrelu(a) @ Wg2    ; a = aggregate(t) ; stats(a)
//   L3: t = bnrelu(a) @ Wm1    ; stats(t)   (N x 256)
//   L4: a = bnrelu(t) @ Wm2    ; stats(a)
//   out = sigmoid( dot(bnrelu(a), Wo) + bo )
// BN+ReLU is applied lazily on the consumer GEMM's A-tile load.
// ---------------------------------------------------------------------------

// ---------------- CSR build ----------------
__global__ void degree_kernel(const int* __restrict__ dst, int* __restrict__ deg, int E) {
    int i = blockIdx.x * blockDim.x + threadIdx.x;
    if (i < E) atomicAdd(&deg[dst[i]], 1);
}

__global__ void dinv_kernel(const int* __restrict__ deg, float* __restrict__ dinv, int N) {
    int i = blockIdx.x * blockDim.x + threadIdx.x;
    if (i < N) dinv[i] = rsqrtf((float)(deg[i] + 1));
}

__global__ void blocksum_kernel(const int* __restrict__ deg, int* __restrict__ bsum, int N) {
    __shared__ int sh[256];
    int tid = threadIdx.x;
    int base = blockIdx.x * 1024 + tid * 4;
    int s = 0;
    #pragma unroll
    for (int j = 0; j < 4; ++j) { int idx = base + j; if (idx < N) s += deg[idx]; }
    sh[tid] = s; __syncthreads();
    for (int off = 128; off > 0; off >>= 1) {
        if (tid < off) sh[tid] += sh[tid + off];
        __syncthreads();
    }
    if (tid == 0) bsum[blockIdx.x] = sh[0];
}

__global__ void scan_bsum_kernel(int* bsum, int nb) {
    if (threadIdx.x == 0 && blockIdx.x == 0) {
        int run = 0;
        for (int i = 0; i < nb; ++i) { int v = bsum[i]; bsum[i] = run; run += v; }
    }
}

__global__ void scanwrite_kernel(const int* __restrict__ deg, const int* __restrict__ bsumex,
                                 int* __restrict__ row_ptr, int* __restrict__ cursor,
                                 int N, int Etot) {
    __shared__ int sh[256];
    int tid = threadIdx.x;
    int base = blockIdx.x * 1024 + tid * 4;
    int v[4]; int tsum = 0;
    #pragma unroll
    for (int j = 0; j < 4; ++j) { int idx = base + j; v[j] = (idx < N) ? deg[idx] : 0; tsum += v[j]; }
    sh[tid] = tsum; __syncthreads();
    for (int off = 1; off < 256; off <<= 1) {
        int x = (tid >= off) ? sh[tid - off] : 0;
        __syncthreads();
        sh[tid] += x;
        __syncthreads();
    }
    int run = sh[tid] - tsum + bsumex[blockIdx.x];
    #pragma unroll
    for (int j = 0; j < 4; ++j) {
        int idx = base + j;
        if (idx < N) { row_ptr[idx] = run; cursor[idx] = run; }
        run += v[j];
    }
    if (blockIdx.x == 0 && tid == 0) row_ptr[N] = Etot;
}

__global__ void scatter_kernel(const int* __restrict__ src, const int* __restrict__ dst,
                               int* __restrict__ cursor, int* __restrict__ edge_src, int E) {
    int i = blockIdx.x * blockDim.x + threadIdx.x;
    if (i < E) {
        int d = dst[i];
        int pos = atomicAdd(&cursor[d], 1);
        edge_src[pos] = src[i];
    }
}

// ---------------- GEMM: C[nrows][FO] = act(A[nrows][K]) @ W[K][FO] ----------------
// act (per A-column k): v*scale[k]+shift[k], relu.  Tile 128x128x32, 8x8/thread.
template<bool ACT>
__global__ __launch_bounds__(256)
void gemm_kernel(const float* __restrict__ A, const float* __restrict__ W,
                 float* __restrict__ C, int nrows, int K, int FO,
                 const float* __restrict__ scale, const float* __restrict__ shift)
{
    __shared__ float As[32][132];   // [k][m], padded
    __shared__ float Ws[32][132];   // [k][n], padded (132%4==0 keeps float4 alignment)
    const int tid = threadIdx.x;
    const int row0 = blockIdx.x * 128;
    const int c0 = blockIdx.y * 128;
    const int tx = tid & 15, ty = tid >> 4;
    float acc[8][8];
    #pragma unroll
    for (int i = 0; i < 8; ++i)
        #pragma unroll
        for (int j = 0; j < 8; ++j) acc[i][j] = 0.f;

    for (int k0 = 0; k0 < K; k0 += 32) {
        #pragma unroll
        for (int p = 0; p < 4; ++p) {          // A tile: 128 rows x 32 k
            int q = p * 256 + tid;
            int r = q >> 3;
            int kq = (q & 7) * 4;
            int gr = row0 + r;
            float4 v = make_float4(0.f, 0.f, 0.f, 0.f);
            if (gr < nrows) {
                v = *(const float4*)&A[(size_t)gr * K + k0 + kq];
                if (ACT) {
                    float4 sc = *(const float4*)&scale[k0 + kq];
                    float4 sf = *(const float4*)&shift[k0 + kq];
                    v.x = fmaxf(fmaf(v.x, sc.x, sf.x), 0.f);
                    v.y = fmaxf(fmaf(v.y, sc.y, sf.y), 0.f);
                    v.z = fmaxf(fmaf(v.z, sc.z, sf.z), 0.f);
                    v.w = fmaxf(fmaf(v.w, sc.w, sf.w), 0.f);
                }
            }
            As[kq + 0][r] = v.x; As[kq + 1][r] = v.y;
            As[kq + 2][r] = v.z; As[kq + 3][r] = v.w;
        }
        #pragma unroll
        for (int p = 0; p < 4; ++p) {          // W tile: 32 k x 128 cols
            int q = p * 256 + tid;
            int r = q >> 5;
            int cq = (q & 31) * 4;
            *(float4*)&Ws[r][cq] = *(const float4*)&W[(size_t)(k0 + r) * FO + c0 + cq];
        }
        __syncthreads();
        #pragma unroll
        for (int kk = 0; kk < 32; ++kk) {
            float4 a0 = *(const float4*)&As[kk][ty * 4];
            float4 a1 = *(const float4*)&As[kk][64 + ty * 4];
            float4 b0 = *(const float4*)&Ws[kk][tx * 4];
            float4 b1 = *(const float4*)&Ws[kk][64 + tx * 4];
            float a[8] = {a0.x, a0.y, a0.z, a0.w, a1.x, a1.y, a1.z, a1.w};
            float b[8] = {b0.x, b0.y, b0.z, b0.w, b1.x, b1.y, b1.z, b1.w};
            #pragma unroll
            for (int i = 0; i < 8; ++i)
                #pragma unroll
                for (int j = 0; j < 8; ++j)
                    acc[i][j] = fmaf(a[i], b[j], acc[i][j]);
        }
        __syncthreads();
    }
    #pragma unroll
    for (int i = 0; i < 8; ++i) {
        int r = (i < 4) ? (ty * 4 + i) : (64 + ty * 4 + i - 4);
        int gr = row0 + r;
        if (gr < nrows) {
            float4 o0 = make_float4(acc[i][0], acc[i][1], acc[i][2], acc[i][3]);
            float4 o1 = make_float4(acc[i][4], acc[i][5], acc[i][6], acc[i][7]);
            *(float4*)&C[(size_t)gr * FO + c0 + tx * 4] = o0;
            *(float4*)&C[(size_t)gr * FO + c0 + 64 + tx * 4] = o1;
        }
    }
}

// ---------------- edge aggregation (CSR, one wave per node) ----------------
// A[i] = dinv[i] * sum_{e in in(i)} dinv[src_e]*T[src_e]  +  dinv[i]^2 * T[i]
__global__ void agg_kernel(const float* __restrict__ T, float* __restrict__ Aout,
                           const float* __restrict__ dinv,
                           const int* __restrict__ row_ptr, const int* __restrict__ edge_src,
                           int nrows)
{
    int gw = (blockIdx.x * blockDim.x + threadIdx.x) >> 6;
    int lane = threadIdx.x & 63;
    int nw = (gridDim.x * blockDim.x) >> 6;
    int c = lane * 2;
    for (int i = gw; i < nrows; i += nw) {
        float di = dinv[i];
        int e0 = row_ptr[i], e1 = row_ptr[i + 1];
        float ax = 0.f, ay = 0.f;
        for (int e = e0; e < e1; ++e) {
            int s = edge_src[e];
            float ws = dinv[s];
            float2 v = *(const float2*)&T[(size_t)s * 128 + c];
            ax = fmaf(ws, v.x, ax);
            ay = fmaf(ws, v.y, ay);
        }
        float2 self = *(const float2*)&T[(size_t)i * 128 + c];
        float2 o;
        o.x = fmaf(di, ax, di * di * self.x);
        o.y = fmaf(di, ay, di * di * self.y);
        *(float2*)&Aout[(size_t)i * 128 + c] = o;
    }
}

// ---------------- per-column sum / sumsq ----------------
__global__ void colstats_kernel(const float* __restrict__ X, int nrows, int F, int rpb,
                                float* __restrict__ colsum, float* __restrict__ colsq)
{
    __shared__ float ss[256], sq[256];
    int tid = threadIdx.x;
    int c = tid & (F - 1);
    int roff = tid / F;
    int rstep = 256 / F;
    int r0 = blockIdx.x * rpb;
    int r1 = min(nrows, r0 + rpb);
    float s = 0.f, q = 0.f;
    for (int r = r0 + roff; r < r1; r += rstep) {
        float v = X[(size_t)r * F + c];
        s += v; q += v * v;
    }
    ss[tid] = s; sq[tid] = q;
    __syncthreads();
    if (tid < F) {
        float S = ss[tid], Q = sq[tid];
        for (int k = tid + F; k < 256; k += F) { S += ss[k]; Q += sq[k]; }
        atomicAdd(&colsum[tid], S);
        atomicAdd(&colsq[tid], Q);
    }
}

__global__ void bnparam_kernel(const float* __restrict__ colsum, const float* __restrict__ colsq,
                               const float* __restrict__ g, const float* __restrict__ be,
                               float* __restrict__ scale, float* __restrict__ shift,
                               int F, float invN)
{
    int c = blockIdx.x * blockDim.x + threadIdx.x;
    if (c < F) {
        float mean = colsum[c] * invN;
        float var = colsq[c] * invN - mean * mean;
        float rs = rsqrtf(var + 1e-5f);
        float sc = g[c] * rs;
        scale[c] = sc;
        shift[c] = be[c] - mean * sc;
    }
}

// ---------------- final: sigmoid( dot(bnrelu(A[i]), Wo) + bo ) ----------------
__global__ void final_kernel(const float* __restrict__ A, const float* __restrict__ Wo,
                             const float* __restrict__ bo,
                             const float* __restrict__ scale, const float* __restrict__ shift,
                             float* __restrict__ out, int nrows)
{
    int gw = (blockIdx.x * blockDim.x + threadIdx.x) >> 6;
    int lane = threadIdx.x & 63;
    int nw = (gridDim.x * blockDim.x) >> 6;
    int c = lane * 2;
    float2 w = *(const float2*)&Wo[c];
    float2 sc = *(const float2*)&scale[c];
    float2 sf = *(const float2*)&shift[c];
    float bias = bo[0];
    for (int i = gw; i < nrows; i += nw) {
        float2 v = *(const float2*)&A[(size_t)i * 128 + c];
        float x = fmaxf(fmaf(v.x, sc.x, sf.x), 0.f) * w.x
                + fmaxf(fmaf(v.y, sc.y, sf.y), 0.f) * w.y;
        #pragma unroll
        for (int off = 32; off > 0; off >>= 1) x += __shfl_down(x, off);
        if (lane == 0) out[i] = 1.f / (1.f + expf(-(x + bias)));
    }
}

extern "C" void kernel_launch(void* const* d_in, const int* in_sizes, int n_in,
                              void* d_out, int out_size, void* d_ws, size_t ws_size,
                              hipStream_t stream)
{
    const float* x   = (const float*)d_in[0];
    const int* ei    = (const int*)d_in[1];
    const float* Wg1 = (const float*)d_in[2];
    const float* g1  = (const float*)d_in[4];
    const float* be1 = (const float*)d_in[5];
    const float* Wg2 = (const float*)d_in[6];
    const float* g2  = (const float*)d_in[8];
    const float* be2 = (const float*)d_in[9];
    const float* Wm1 = (const float*)d_in[10];
    const float* g3  = (const float*)d_in[12];
    const float* be3 = (const float*)d_in[13];
    const float* Wm2 = (const float*)d_in[14];
    const float* g4  = (const float*)d_in[16];
    const float* be4 = (const float*)d_in[17];
    const float* Wo  = (const float*)d_in[18];
    const float* bo  = (const float*)d_in[19];

    const int N = in_sizes[0] / 128;
    const int E = in_sizes[1] / 2;
    const int* srcv = ei;
    const int* dstv = ei + E;

    char* p = (char*)d_ws;
    auto alloc = [&](size_t bytes) { void* r = (void*)p; p += (bytes + 255) & ~(size_t)255; return r; };
    float* T       = (float*)alloc((size_t)N * 256 * 4);   // GEMM outputs (up to N x 256)
    float* Abuf    = (float*)alloc((size_t)N * 128 * 4);   // aggregate / final activations
    int*   deg     = (int*)alloc((size_t)N * 4);
    float* dinv    = (float*)alloc((size_t)N * 4);
    int*   row_ptr = (int*)alloc((size_t)(N + 1) * 4);
    int*   cursor  = (int*)alloc((size_t)N * 4);
    int*   edge_src= (int*)alloc((size_t)E * 4);
    int*   bsum    = (int*)alloc(4096);
    float* colsum  = (float*)alloc(512 * 4);               // [0:256)=sum, [256:512)=sumsq
    float* colsq   = colsum + 256;
    float* scale   = (float*)alloc(256 * 4);
    float* shift   = (float*)alloc(256 * 4);

    const int rpb = (N + 255) / 256;   // rows per colstats block (256 blocks)
    const float invN = 1.f / (float)N;

    // --- CSR build ---
    hipMemsetAsync(deg, 0, (size_t)N * 4, stream);
    degree_kernel<<<(E + 255) / 256, 256, 0, stream>>>(dstv, deg, E);
    dinv_kernel<<<(N + 255) / 256, 256, 0, stream>>>(deg, dinv, N);
    int nb = (N + 1023) / 1024;
    blocksum_kernel<<<nb, 256, 0, stream>>>(deg, bsum, N);
    scan_bsum_kernel<<<1, 64, 0, stream>>>(bsum, nb);
    scanwrite_kernel<<<nb, 256, 0, stream>>>(deg, bsum, row_ptr, cursor, N, E);
    scatter_kernel<<<(E + 255) / 256, 256, 0, stream>>>(srcv, dstv, cursor, edge_src, E);

    dim3 gemm_g((N + 127) / 128, 1);
    dim3 gemm_g2((N + 127) / 128, 2);

    // --- L1: GCNConv 1 ---
    gemm_kernel<false><<<gemm_g, 256, 0, stream>>>(x, Wg1, T, N, 128, 128, nullptr, nullptr);
    agg_kernel<<<2048, 256, 0, stream>>>(T, Abuf, dinv, row_ptr, edge_src, N);
    hipMemsetAsync(colsum, 0, 512 * 4, stream);
    colstats_kernel<<<256, 256, 0, stream>>>(Abuf, N, 128, rpb, colsum, colsq);
    bnparam_kernel<<<1, 256, 0, stream>>>(colsum, colsq, g1, be1, scale, shift, 128, invN);

    // --- L2: GCNConv 2 ---
    gemm_kernel<true><<<gemm_g, 256, 0, stream>>>(Abuf, Wg2, T, N, 128, 128, scale, shift);
    agg_kernel<<<2048, 256, 0, stream>>>(T, Abuf, dinv, row_ptr, edge_src, N);
    hipMemsetAsync(colsum, 0, 512 * 4, stream);
    colstats_kernel<<<256, 256, 0, stream>>>(Abuf, N, 128, rpb, colsum, colsq);
    bnparam_kernel<<<1, 256, 0, stream>>>(colsum, colsq, g2, be2, scale, shift, 128, invN);

    // --- L3: MLP 128 -> 256 ---
    gemm_kernel<true><<<gemm_g2, 256, 0, stream>>>(Abuf, Wm1, T, N, 128, 256, scale, shift);
    hipMemsetAsync(colsum, 0, 512 * 4, stream);
    colstats_kernel<<<256, 256, 0, stream>>>(T, N, 256, rpb, colsum, colsq);
    bnparam_kernel<<<1, 256, 0, stream>>>(colsum, colsq, g3, be3, scale, shift, 256, invN);

    // --- L4: MLP 256 -> 128 ---
    gemm_kernel<true><<<gemm_g, 256, 0, stream>>>(T, Wm2, Abuf, N, 256, 128, scale, shift);
    hipMemsetAsync(colsum, 0, 512 * 4, stream);
    colstats_kernel<<<256, 256, 0, stream>>>(Abuf, N, 128, rpb, colsum, colsq);
    bnparam_kernel<<<1, 256, 0, stream>>>(colsum, colsq, g4, be4, scale, shift, 128, invN);

    // --- output ---
    final_kernel<<<1024, 256, 0, stream>>>(Abuf, Wo, bo, scale, shift, (float*)d_out, N);
}

// Round 2
// 1027.024 us; speedup vs baseline: 1.1979x; 1.1979x over previous
//
#include <hip/hip_runtime.h>
#include <hip/hip_bf16.h>
#include <math.h>

// ---------------------------------------------------------------------------
// GCN classifier pipeline.
//   L1: t = x @ Wg1            ; a = aggregate(t) ; stats(a)  (bias cancels in BN)
//   L2: t = bnrelu(a) @ Wg2    ; a = aggregate(t) ; stats(a)
//   L3: t = bnrelu(a) @ Wm1    ; stats(t)   (N x 256)
//   L4: a = bnrelu(t) @ Wm2    ; stats(a)
//   out = sigmoid( dot(bnrelu(a), Wo) + bo )
// GEMMs: split-bf16 (hi+lo) MFMA, 3 products, fp32-class accuracy.
// BN+ReLU applied lazily on the consumer GEMM's A-tile load.
// ---------------------------------------------------------------------------

typedef __attribute__((ext_vector_type(8))) short bf16x8;
typedef __attribute__((ext_vector_type(4))) float f32x4;

__device__ inline void split_bf16(float x, ushort& h, ushort& l) {
    union { float f; unsigned u; } a; a.f = x;
    unsigned r = (a.u + 0x7FFFu + ((a.u >> 16) & 1u)) >> 16;   // rne to bf16
    h = (ushort)r;
    union { unsigned u; float f; } hb; hb.u = r << 16;
    float lo = x - hb.f;
    union { float f; unsigned u; } b; b.f = lo;
    unsigned r2 = (b.u + 0x7FFFu + ((b.u >> 16) & 1u)) >> 16;
    l = (ushort)r2;
}

// ---------------- CSR build ----------------
__global__ void degree_kernel(const int* __restrict__ dst, int* __restrict__ deg, int E) {
    int i = blockIdx.x * blockDim.x + threadIdx.x;
    if (i < E) atomicAdd(&deg[dst[i]], 1);
}

__global__ void dinv_kernel(const int* __restrict__ deg, float* __restrict__ dinv, int N) {
    int i = blockIdx.x * blockDim.x + threadIdx.x;
    if (i < N) dinv[i] = rsqrtf((float)(deg[i] + 1));
}

__global__ void blocksum_kernel(const int* __restrict__ deg, int* __restrict__ bsum, int N) {
    __shared__ int sh[256];
    int tid = threadIdx.x;
    int base = blockIdx.x * 1024 + tid * 4;
    int s = 0;
    #pragma unroll
    for (int j = 0; j < 4; ++j) { int idx = base + j; if (idx < N) s += deg[idx]; }
    sh[tid] = s; __syncthreads();
    for (int off = 128; off > 0; off >>= 1) {
        if (tid < off) sh[tid] += sh[tid + off];
        __syncthreads();
    }
    if (tid == 0) bsum[blockIdx.x] = sh[0];
}

__global__ void scan_bsum_kernel(int* bsum, int nb) {
    if (threadIdx.x == 0 && blockIdx.x == 0) {
        int run = 0;
        for (int i = 0; i < nb; ++i) { int v = bsum[i]; bsum[i] = run; run += v; }
    }
}

__global__ void scanwrite_kernel(const int* __restrict__ deg, const int* __restrict__ bsumex,
                                 int* __restrict__ row_ptr, int* __restrict__ cursor,
                                 int N, int Etot) {
    __shared__ int sh[256];
    int tid = threadIdx.x;
    int base = blockIdx.x * 1024 + tid * 4;
    int v[4]; int tsum = 0;
    #pragma unroll
    for (int j = 0; j < 4; ++j) { int idx = base + j; v[j] = (idx < N) ? deg[idx] : 0; tsum += v[j]; }
    sh[tid] = tsum; __syncthreads();
    for (int off = 1; off < 256; off <<= 1) {
        int x = (tid >= off) ? sh[tid - off] : 0;
        __syncthreads();
        sh[tid] += x;
        __syncthreads();
    }
    int run = sh[tid] - tsum + bsumex[blockIdx.x];
    #pragma unroll
    for (int j = 0; j < 4; ++j) {
        int idx = base + j;
        if (idx < N) { row_ptr[idx] = run; cursor[idx] = run; }
        run += v[j];
    }
    if (blockIdx.x == 0 && tid == 0) row_ptr[N] = Etot;
}

__global__ void scatter_kernel(const int* __restrict__ src, const int* __restrict__ dst,
                               int* __restrict__ cursor, int* __restrict__ edge_src, int E) {
    int i = blockIdx.x * blockDim.x + threadIdx.x;
    if (i < E) {
        int d = dst[i];
        int pos = atomicAdd(&cursor[d], 1);
        edge_src[pos] = src[i];
    }
}

// ---------------- W pre-split into fragment-native layout ----------------
// W2[cb][kg][ci][j] = split(W[kg*8+j][cb*128+ci]),  flat = ((cb*nkg+kg)*128+ci)*8+j
__global__ void wsplit_kernel(const float* __restrict__ W, ushort* __restrict__ Wh,
                              ushort* __restrict__ Wl, int K, int FO) {
    int t = blockIdx.x * 256 + threadIdx.x;
    if (t >= K * FO) return;
    int j   = t & 7;
    int ci  = (t >> 3) & 127;
    int rest = t >> 10;
    int nkg = K >> 3;
    int kg  = rest % nkg;
    int cb  = rest / nkg;
    float w = W[(size_t)(kg * 8 + j) * FO + cb * 128 + ci];
    ushort h, l; split_bf16(w, h, l);
    Wh[t] = h; Wl[t] = l;
}

// ---------------- GEMM: C[nrows][FO] = act(A[nrows][K]) @ W[K][FO] ----------------
// 128x128 block, 4 waves (2x2), 64x64 per wave, mfma_f32_16x16x32_bf16, split hi/lo.
// LDS A layout: [kg][row][8] with plane stride 1032 ushorts (2064 B) -> conflict-free b128.
#define AIDX(kg, r, j) ((kg) * 1032 + (r) * 8 + (j))

template<bool ACT>
__global__ __launch_bounds__(256)
void gemm_mfma_kernel(const float* __restrict__ A, const ushort* __restrict__ W2h,
                      const ushort* __restrict__ W2l, float* __restrict__ C,
                      int nrows, int K, int FO,
                      const float* __restrict__ scale, const float* __restrict__ shift)
{
    __shared__ ushort AsH[4 * 1032 + 8];
    __shared__ ushort AsL[4 * 1032 + 8];
    const int tid  = threadIdx.x;
    const int lane = tid & 63;
    const int wid  = tid >> 6;
    const int wm   = wid & 1, wn = wid >> 1;
    const int row0 = blockIdx.x * 128;
    const int cb   = blockIdx.y;
    const int c0   = cb * 128;
    const int nkg  = K >> 3;
    const int l15  = lane & 15;
    const int l4   = lane >> 4;

    f32x4 zero = {0.f, 0.f, 0.f, 0.f};
    f32x4 acc[4][4];
    #pragma unroll
    for (int m = 0; m < 4; ++m)
        #pragma unroll
        for (int n = 0; n < 4; ++n) acc[m][n] = zero;

    for (int k0 = 0; k0 < K; k0 += 32) {
        // stage A tile (128 rows x 32 k), act + split -> LDS
        #pragma unroll
        for (int p = 0; p < 4; ++p) {
            int q  = p * 256 + tid;
            int r  = q >> 3;
            int kq = (q & 7) * 4;          // 0,4,...,28
            int gr = row0 + r;
            float4 v = make_float4(0.f, 0.f, 0.f, 0.f);
            if (gr < nrows) {
                v = *(const float4*)&A[(size_t)gr * K + k0 + kq];
                if (ACT) {
                    float4 sc = *(const float4*)&scale[k0 + kq];
                    float4 sf = *(const float4*)&shift[k0 + kq];
                    v.x = fmaxf(fmaf(v.x, sc.x, sf.x), 0.f);
                    v.y = fmaxf(fmaf(v.y, sc.y, sf.y), 0.f);
                    v.z = fmaxf(fmaf(v.z, sc.z, sf.z), 0.f);
                    v.w = fmaxf(fmaf(v.w, sc.w, sf.w), 0.f);
                }
            }
            ushort h[4], l[4];
            split_bf16(v.x, h[0], l[0]); split_bf16(v.y, h[1], l[1]);
            split_bf16(v.z, h[2], l[2]); split_bf16(v.w, h[3], l[3]);
            int idx = AIDX(kq >> 3, r, kq & 7);
            union { uint2 u; ushort s[4]; } ph, pl;
            ph.s[0] = h[0]; ph.s[1] = h[1]; ph.s[2] = h[2]; ph.s[3] = h[3];
            pl.s[0] = l[0]; pl.s[1] = l[1]; pl.s[2] = l[2]; pl.s[3] = l[3];
            *(uint2*)&AsH[idx] = ph.u;
            *(uint2*)&AsL[idx] = pl.u;
        }
        __syncthreads();

        const int kgbase = k0 >> 3;
        bf16x8 bh[4], bl[4];
        #pragma unroll
        for (int n = 0; n < 4; ++n) {
            int ci = wn * 64 + n * 16 + l15;
            size_t off = (((size_t)(cb * nkg + kgbase + l4)) * 128 + ci) * 8;
            bh[n] = *(const bf16x8*)&W2h[off];
            bl[n] = *(const bf16x8*)&W2l[off];
        }
        bf16x8 ah[4], al[4];
        #pragma unroll
        for (int m = 0; m < 4; ++m) {
            int idx = AIDX(l4, wm * 64 + m * 16 + l15, 0);
            ah[m] = *(const bf16x8*)&AsH[idx];
            al[m] = *(const bf16x8*)&AsL[idx];
        }
        #pragma unroll
        for (int m = 0; m < 4; ++m)
            #pragma unroll
            for (int n = 0; n < 4; ++n) {
                acc[m][n] = __builtin_amdgcn_mfma_f32_16x16x32_bf16(ah[m], bh[n], acc[m][n], 0, 0, 0);
                acc[m][n] = __builtin_amdgcn_mfma_f32_16x16x32_bf16(ah[m], bl[n], acc[m][n], 0, 0, 0);
                acc[m][n] = __builtin_amdgcn_mfma_f32_16x16x32_bf16(al[m], bh[n], acc[m][n], 0, 0, 0);
            }
        __syncthreads();
    }

    // epilogue: C write (row = (lane>>4)*4 + reg, col = lane&15 within fragment)
    #pragma unroll
    for (int m = 0; m < 4; ++m) {
        int rbase = row0 + wm * 64 + m * 16 + l4 * 4;
        #pragma unroll
        for (int r = 0; r < 4; ++r) {
            int gr = rbase + r;
            if (gr < nrows) {
                #pragma unroll
                for (int n = 0; n < 4; ++n) {
                    int gc = c0 + wn * 64 + n * 16 + l15;
                    C[(size_t)gr * FO + gc] = acc[m][n][r];
                }
            }
        }
    }
}

// ---------------- edge aggregation (CSR, one wave per node, shfl-broadcast) ------
// A[i] = dinv[i] * sum_e dinv[src_e]*T[src_e] + dinv[i]^2 * T[i]
__global__ void agg_kernel(const float* __restrict__ T, float* __restrict__ Aout,
                           const float* __restrict__ dinv,
                           const int* __restrict__ row_ptr, const int* __restrict__ edge_src,
                           int nrows)
{
    int gw = (blockIdx.x * blockDim.x + threadIdx.x) >> 6;
    int lane = threadIdx.x & 63;
    int nw = (gridDim.x * blockDim.x) >> 6;
    int c = lane * 2;
    for (int i = gw; i < nrows; i += nw) {
        float di = dinv[i];
        int e0 = row_ptr[i], e1 = row_ptr[i + 1];
        float ax = 0.f, ay = 0.f;
        for (int ch = e0; ch < e1; ch += 64) {
            int rem = e1 - ch;                 // >0
            int es = i; float w = 0.f;         // safe addr, zero weight for pad lanes
            if (lane < rem) { es = edge_src[ch + lane]; w = dinv[es]; }
            int cnt = min(rem, 64);
            int rcnt = (cnt + 3) & ~3;
            for (int j = 0; j < rcnt; j += 4) {
                int   s0 = __shfl(es, j),     s1 = __shfl(es, j + 1);
                int   s2 = __shfl(es, j + 2), s3 = __shfl(es, j + 3);
                float w0 = __shfl(w, j),      w1 = __shfl(w, j + 1);
                float w2 = __shfl(w, j + 2),  w3 = __shfl(w, j + 3);
                float2 v0 = *(const float2*)&T[(size_t)s0 * 128 + c];
                float2 v1 = *(const float2*)&T[(size_t)s1 * 128 + c];
                float2 v2 = *(const float2*)&T[(size_t)s2 * 128 + c];
                float2 v3 = *(const float2*)&T[(size_t)s3 * 128 + c];
                ax = fmaf(w0, v0.x, ax); ay = fmaf(w0, v0.y, ay);
                ax = fmaf(w1, v1.x, ax); ay = fmaf(w1, v1.y, ay);
                ax = fmaf(w2, v2.x, ax); ay = fmaf(w2, v2.y, ay);
                ax = fmaf(w3, v3.x, ax); ay = fmaf(w3, v3.y, ay);
            }
        }
        float2 self = *(const float2*)&T[(size_t)i * 128 + c];
        float2 o;
        o.x = fmaf(di, ax, di * di * self.x);
        o.y = fmaf(di, ay, di * di * self.y);
        *(float2*)&Aout[(size_t)i * 128 + c] = o;
    }
}

// ---------------- per-column sum / sumsq ----------------
__global__ void colstats_kernel(const float* __restrict__ X, int nrows, int F, int rpb,
                                float* __restrict__ colsum, float* __restrict__ colsq)
{
    __shared__ float ss[256], sq[256];
    int tid = threadIdx.x;
    int c = tid & (F - 1);
    int roff = tid / F;
    int rstep = 256 / F;
    int r0 = blockIdx.x * rpb;
    int r1 = min(nrows, r0 + rpb);
    float s = 0.f, q = 0.f;
    for (int r = r0 + roff; r < r1; r += rstep) {
        float v = X[(size_t)r * F + c];
        s += v; q += v * v;
    }
    ss[tid] = s; sq[tid] = q;
    __syncthreads();
    if (tid < F) {
        float S = ss[tid], Q = sq[tid];
        for (int k = tid + F; k < 256; k += F) { S += ss[k]; Q += sq[k]; }
        atomicAdd(&colsum[tid], S);
        atomicAdd(&colsq[tid], Q);
    }
}

__global__ void bnparam_kernel(const float* __restrict__ colsum, const float* __restrict__ colsq,
                               const float* __restrict__ g, const float* __restrict__ be,
                               float* __restrict__ scale, float* __restrict__ shift,
                               int F, float invN)
{
    int c = blockIdx.x * blockDim.x + threadIdx.x;
    if (c < F) {
        float mean = colsum[c] * invN;
        float var = colsq[c] * invN - mean * mean;
        float rs = rsqrtf(var + 1e-5f);
        float sc = g[c] * rs;
        scale[c] = sc;
        shift[c] = be[c] - mean * sc;
    }
}

// ---------------- final: sigmoid( dot(bnrelu(A[i]), Wo) + bo ) ----------------
__global__ void final_kernel(const float* __restrict__ A, const float* __restrict__ Wo,
                             const float* __restrict__ bo,
                             const float* __restrict__ scale, const float* __restrict__ shift,
                             float* __restrict__ out, int nrows)
{
    int gw = (blockIdx.x * blockDim.x + threadIdx.x) >> 6;
    int lane = threadIdx.x & 63;
    int nw = (gridDim.x * blockDim.x) >> 6;
    int c = lane * 2;
    float2 w = *(const float2*)&Wo[c];
    float2 sc = *(const float2*)&scale[c];
    float2 sf = *(const float2*)&shift[c];
    float bias = bo[0];
    for (int i = gw; i < nrows; i += nw) {
        float2 v = *(const float2*)&A[(size_t)i * 128 + c];
        float x = fmaxf(fmaf(v.x, sc.x, sf.x), 0.f) * w.x
                + fmaxf(fmaf(v.y, sc.y, sf.y), 0.f) * w.y;
        #pragma unroll
        for (int off = 32; off > 0; off >>= 1) x += __shfl_down(x, off);
        if (lane == 0) out[i] = 1.f / (1.f + expf(-(x + bias)));
    }
}

extern "C" void kernel_launch(void* const* d_in, const int* in_sizes, int n_in,
                              void* d_out, int out_size, void* d_ws, size_t ws_size,
                              hipStream_t stream)
{
    const float* x   = (const float*)d_in[0];
    const int* ei    = (const int*)d_in[1];
    const float* Wg1 = (const float*)d_in[2];
    const float* g1  = (const float*)d_in[4];
    const float* be1 = (const float*)d_in[5];
    const float* Wg2 = (const float*)d_in[6];
    const float* g2  = (const float*)d_in[8];
    const float* be2 = (const float*)d_in[9];
    const float* Wm1 = (const float*)d_in[10];
    const float* g3  = (const float*)d_in[12];
    const float* be3 = (const float*)d_in[13];
    const float* Wm2 = (const float*)d_in[14];
    const float* g4  = (const float*)d_in[16];
    const float* be4 = (const float*)d_in[17];
    const float* Wo  = (const float*)d_in[18];
    const float* bo  = (const float*)d_in[19];

    const int N = in_sizes[0] / 128;
    const int E = in_sizes[1] / 2;
    const int* srcv = ei;
    const int* dstv = ei + E;

    char* p = (char*)d_ws;
    auto alloc = [&](size_t bytes) { void* r = (void*)p; p += (bytes + 255) & ~(size_t)255; return r; };
    float* T       = (float*)alloc((size_t)N * 256 * 4);   // GEMM outputs (up to N x 256)
    float* Abuf    = (float*)alloc((size_t)N * 128 * 4);   // aggregate / final activations
    int*   deg     = (int*)alloc((size_t)N * 4);
    float* dinv    = (float*)alloc((size_t)N * 4);
    int*   row_ptr = (int*)alloc((size_t)(N + 1) * 4);
    int*   cursor  = (int*)alloc((size_t)N * 4);
    int*   edge_src= (int*)alloc((size_t)E * 4);
    int*   bsum    = (int*)alloc(4096);
    float* colsum  = (float*)alloc(512 * 4);               // [0:256)=sum, [256:512)=sumsq
    float* colsq   = colsum + 256;
    float* scale   = (float*)alloc(256 * 4);
    float* shift   = (float*)alloc(256 * 4);
    ushort* W2h    = (ushort*)alloc(32768 * 2);            // split weights, frag-native layout
    ushort* W2l    = (ushort*)alloc(32768 * 2);

    const int rpb = (N + 255) / 256;
    const float invN = 1.f / (float)N;

    // --- CSR build ---
    hipMemsetAsync(deg, 0, (size_t)N * 4, stream);
    degree_kernel<<<(E + 255) / 256, 256, 0, stream>>>(dstv, deg, E);
    dinv_kernel<<<(N + 255) / 256, 256, 0, stream>>>(deg, dinv, N);
    int nb = (N + 1023) / 1024;
    blocksum_kernel<<<nb, 256, 0, stream>>>(deg, bsum, N);
    scan_bsum_kernel<<<1, 64, 0, stream>>>(bsum, nb);
    scanwrite_kernel<<<nb, 256, 0, stream>>>(deg, bsum, row_ptr, cursor, N, E);
    scatter_kernel<<<(E + 255) / 256, 256, 0, stream>>>(srcv, dstv, cursor, edge_src, E);

    const int gx = (N + 127) / 128;
    dim3 gemm_g(gx, 1);
    dim3 gemm_g2(gx, 2);

    // --- L1: GCNConv 1 (x @ Wg1) ---
    wsplit_kernel<<<(128 * 128 + 255) / 256, 256, 0, stream>>>(Wg1, W2h, W2l, 128, 128);
    gemm_mfma_kernel<false><<<gemm_g, 256, 0, stream>>>(x, W2h, W2l, T, N, 128, 128, nullptr, nullptr);
    agg_kernel<<<2048, 256, 0, stream>>>(T, Abuf, dinv, row_ptr, edge_src, N);
    hipMemsetAsync(colsum, 0, 512 * 4, stream);
    colstats_kernel<<<256, 256, 0, stream>>>(Abuf, N, 128, rpb, colsum, colsq);
    bnparam_kernel<<<1, 256, 0, stream>>>(colsum, colsq, g1, be1, scale, shift, 128, invN);

    // --- L2: GCNConv 2 ---
    wsplit_kernel<<<(128 * 128 + 255) / 256, 256, 0, stream>>>(Wg2, W2h, W2l, 128, 128);
    gemm_mfma_kernel<true><<<gemm_g, 256, 0, stream>>>(Abuf, W2h, W2l, T, N, 128, 128, scale, shift);
    agg_kernel<<<2048, 256, 0, stream>>>(T, Abuf, dinv, row_ptr, edge_src, N);
    hipMemsetAsync(colsum, 0, 512 * 4, stream);
    colstats_kernel<<<256, 256, 0, stream>>>(Abuf, N, 128, rpb, colsum, colsq);
    bnparam_kernel<<<1, 256, 0, stream>>>(colsum, colsq, g2, be2, scale, shift, 128, invN);

    // --- L3: MLP 128 -> 256 ---
    wsplit_kernel<<<(128 * 256 + 255) / 256, 256, 0, stream>>>(Wm1, W2h, W2l, 128, 256);
    gemm_mfma_kernel<true><<<gemm_g2, 256, 0, stream>>>(Abuf, W2h, W2l, T, N, 128, 256, scale, shift);
    hipMemsetAsync(colsum, 0, 512 * 4, stream);
    colstats_kernel<<<256, 256, 0, stream>>>(T, N, 256, rpb, colsum, colsq);
    bnparam_kernel<<<1, 256, 0, stream>>>(colsum, colsq, g3, be3, scale, shift, 256, invN);

    // --- L4: MLP 256 -> 128 ---
    wsplit_kernel<<<(256 * 128 + 255) / 256, 256, 0, stream>>>(Wm2, W2h, W2l, 256, 128);
    gemm_mfma_kernel<true><<<gemm_g, 256, 0, stream>>>(T, W2h, W2l, Abuf, N, 256, 128, scale, shift);
    hipMemsetAsync(colsum, 0, 512 * 4, stream);
    colstats_kernel<<<256, 256, 0, stream>>>(Abuf, N, 128, rpb, colsum, colsq);
    bnparam_kernel<<<1, 256, 0, stream>>>(colsum, colsq, g4, be4, scale, shift, 128, invN);

    // --- output ---
    final_kernel<<<1024, 256, 0, stream>>>(Abuf, Wo, bo, scale, shift, (float*)d_out, N);
}